// Round 7
// baseline (4247.458 us; speedup 1.0000x reference)
//
#include <hip/hip_runtime.h>
#include <hip/hip_bf16.h>
#include <hip/hip_fp16.h>

// APPNP: h = MLP(x); 10x { h = 0.9 * (D^-1/2 (A+I) D^-1/2) h + 0.1 * h0 }
// fp32 in/out; GEMMs run bf16 MFMA with inline fp32->bf16 conversion.
// R4: byte-diet (bf16 mirror of h, 4B/edge CSR). R5/R8 CSR-build variants
//   REVERTED (atomic serialization / no XCD placement control): direct
//   scatter fill_csr (~160us, 197MB partial-line drain) is structural.
// R7 (GEMM reg-prefetch) REVERTED (VGPR/occupancy). R9: global_load_lds.
// R10: gemm1 2-phase double-buffer -> gemm1 out of top-5. KEEP.
// R11: prop_step phase-major rewrite. Old: one wave/node, random gathers
//   over 12.8MB hinb -> ~30% L2 hit, ~280MB/step from L3 at ~4.5TB/s = the
//   94us floor. New: CSR bucketed by src>>14 (7 slices x 2MB <= 4MB L2);
//   grid fully co-resident (1536 blocks = 6144 waves, no rolling), each wave
//   owns 17 interleaved nodes (acc in regs); all waves sweep buckets in the
//   same order -> per phase the whole GPU gathers from ONE 2MB slice ->
//   L2-resident on every XCD. CSR build: cnt8[(d,src>>14)] + 800K scan
//   (8 elems/thread) + same scatter; dinv from offs8 diffs.

typedef __bf16 bf16x8 __attribute__((ext_vector_type(8)));
typedef float f32x4 __attribute__((ext_vector_type(4)));

static constexpr int IN = 512, HID = 256, OUT = 64;
static constexpr int LDT = 40;   // LDS row stride (bf16 elems) for gemm2
static constexpr int NPW = 17;   // nodes per wave in prop_step
static constexpr int PGRID = 1536;  // prop blocks; waves = PGRID*4 = 6144

static __device__ __forceinline__ ushort f2bf(float f) {
  __hip_bfloat16 b = __float2bfloat16(f);
  return *reinterpret_cast<ushort*>(&b);
}
static __device__ __forceinline__ float bf2f(ushort u) {
  unsigned int x = ((unsigned int)u) << 16;
  return __uint_as_float(x);
}
// decode low-15-bit fp16 (sign=0) weight
static __device__ __forceinline__ float h15f(unsigned int u) {
  ushort hb = (ushort)(u & 0x7FFFu);
  __half h = *reinterpret_cast<__half*>(&hb);
  return __half2float(h);
}

static __device__ __forceinline__ void gload16(const void* g, void* l) {
  __builtin_amdgcn_global_load_lds(
      (const __attribute__((address_space(1))) void*)g,
      (__attribute__((address_space(3))) void*)l, 16, 0, 0);
}

// ---------------- transpose fp32 [K][C] -> bf16 [C][K] ----------------
__global__ void transpose_f32_bf16(const float* __restrict__ in, ushort* __restrict__ out,
                                   int K, int C) {
  int idx = blockIdx.x * 256 + threadIdx.x;
  if (idx < K * C) {
    int n = idx / K, k = idx % K;
    out[idx] = f2bf(in[k * C + n]);
  }
}

// ---------------- GEMM1: h1 = relu(X @ W1 + b1) ----------------
// X [M,512] fp32, W1T [256,512] bf16, h1 [M,256] bf16. Tile 128x128x32.
// global_load_lds into double-buffered LDS; A fp32 in LDS (cvt at frag read).
__global__ __launch_bounds__(256) void gemm1(const float* __restrict__ X,
                                             const ushort* __restrict__ W1T,
                                             const float* __restrict__ b1,
                                             ushort* __restrict__ h1, int M) {
  __shared__ __align__(16) float As[2][128 * 32];   // 2x16KB fp32, chunk-swizzled
  __shared__ __align__(16) ushort Bs[2][128 * 32];  // 2x8KB bf16, chunk-swizzled
  const int tid = threadIdx.x;
  const int m0 = blockIdx.y * 128;
  const int n0 = blockIdx.x * 128;
  const int lane = tid & 63, w = tid >> 6;
  const int wr = w >> 1, wc = w & 1;
  const int lm = lane & 15, lq = lane >> 4;
  const int wbase = w * 64;

  auto STAGE = [&](int k0, int buf) {
#pragma unroll
    for (int i = 0; i < 4; ++i) {
      int idx = i * 256 + tid;
      int row = idx >> 3, ch = idx & 7;
      int gm = m0 + row; gm = gm < M ? gm : M - 1;
      int sch = ch ^ (row & 7);
      gload16(&X[(size_t)gm * IN + k0 + sch * 4], &As[buf][(i * 256 + wbase) * 4]);
    }
#pragma unroll
    for (int i = 0; i < 2; ++i) {
      int idx = i * 256 + tid;
      int row = idx >> 2, ch = idx & 3;
      int sch = ch ^ ((row ^ (row >> 2)) & 3);
      gload16(&W1T[(size_t)(n0 + row) * IN + k0 + sch * 8], &Bs[buf][(i * 256 + wbase) * 8]);
    }
  };

  f32x4 acc[4][4] = {};

  STAGE(0, 0);
  __syncthreads();

  int cur = 0;
  for (int k0 = 0; k0 < IN; k0 += 32) {
    if (k0 + 32 < IN) STAGE(k0 + 32, cur ^ 1);

    bf16x8 af[4], bq[4];
#pragma unroll
    for (int mi = 0; mi < 4; ++mi) {
      int r = wr * 64 + mi * 16 + lm;
      int k7 = r & 7;
      float4 x0 = *reinterpret_cast<const float4*>(&As[cur][r * 32 + ((2 * lq) ^ k7) * 4]);
      float4 x1 = *reinterpret_cast<const float4*>(&As[cur][r * 32 + ((2 * lq + 1) ^ k7) * 4]);
      union { ushort u[8]; bf16x8 v; } cv;
      cv.u[0] = f2bf(x0.x); cv.u[1] = f2bf(x0.y); cv.u[2] = f2bf(x0.z); cv.u[3] = f2bf(x0.w);
      cv.u[4] = f2bf(x1.x); cv.u[5] = f2bf(x1.y); cv.u[6] = f2bf(x1.z); cv.u[7] = f2bf(x1.w);
      af[mi] = cv.v;
    }
#pragma unroll
    for (int ni = 0; ni < 4; ++ni) {
      int r = wc * 64 + ni * 16 + lm;
      int key = (r ^ (r >> 2)) & 3;
      bq[ni] = *reinterpret_cast<const bf16x8*>(&Bs[cur][r * 32 + (lq ^ key) * 8]);
    }
#pragma unroll
    for (int mi = 0; mi < 4; ++mi)
#pragma unroll
      for (int ni = 0; ni < 4; ++ni)
        acc[mi][ni] = __builtin_amdgcn_mfma_f32_16x16x32_bf16(af[mi], bq[ni], acc[mi][ni], 0, 0, 0);

    __syncthreads();
    cur ^= 1;
  }

#pragma unroll
  for (int ni = 0; ni < 4; ++ni) {
    int col = n0 + wc * 64 + ni * 16 + lm;
    float bias = b1[col];
#pragma unroll
    for (int mi = 0; mi < 4; ++mi) {
#pragma unroll
      for (int rg = 0; rg < 4; ++rg) {
        int row = m0 + wr * 64 + mi * 16 + lq * 4 + rg;
        if (row < M) {
          float v = acc[mi][ni][rg] + bias;
          v = v > 0.f ? v : 0.f;
          h1[(size_t)row * HID + col] = f2bf(v);
        }
      }
    }
  }
}

// ---------------- GEMM2: H0 = h1 @ W2 + b2, fp32 + bf16 mirror out ----------------
__global__ __launch_bounds__(256) void gemm2(const ushort* __restrict__ h1,
                                             const ushort* __restrict__ W2T,
                                             const float* __restrict__ b2,
                                             float* __restrict__ H0f,
                                             ushort* __restrict__ H0b, int M) {
  __shared__ __align__(16) ushort As[128 * LDT];
  __shared__ __align__(16) ushort Bs[64 * LDT];
  const int tid = threadIdx.x;
  const int m0 = blockIdx.x * 128;
  const int lane = tid & 63, w = tid >> 6;
  const int lm = lane & 15, lq = lane >> 4;
  const int c = tid & 3, r = tid >> 2;

  f32x4 acc[2][4] = {};

  for (int k0 = 0; k0 < HID; k0 += 32) {
#pragma unroll
    for (int rr = 0; rr < 2; ++rr) {
      int m = r + rr * 64;
      int gm = m0 + m; gm = gm < M ? gm : M - 1;
      *reinterpret_cast<int4*>(&As[m * LDT + c * 8]) =
          *reinterpret_cast<const int4*>(&h1[(size_t)gm * HID + k0 + c * 8]);
    }
    *reinterpret_cast<int4*>(&Bs[r * LDT + c * 8]) =
        *reinterpret_cast<const int4*>(&W2T[(size_t)r * HID + k0 + c * 8]);
    __syncthreads();
    bf16x8 af[2], bq[4];
#pragma unroll
    for (int mi = 0; mi < 2; ++mi)
      af[mi] = *reinterpret_cast<const bf16x8*>(&As[(w * 32 + mi * 16 + lm) * LDT + lq * 8]);
#pragma unroll
    for (int ni = 0; ni < 4; ++ni)
      bq[ni] = *reinterpret_cast<const bf16x8*>(&Bs[(ni * 16 + lm) * LDT + lq * 8]);
#pragma unroll
    for (int mi = 0; mi < 2; ++mi)
#pragma unroll
      for (int ni = 0; ni < 4; ++ni)
        acc[mi][ni] = __builtin_amdgcn_mfma_f32_16x16x32_bf16(af[mi], bq[ni], acc[mi][ni], 0, 0, 0);
    __syncthreads();
  }

#pragma unroll
  for (int ni = 0; ni < 4; ++ni) {
    int col = ni * 16 + lm;
    float bias = b2[col];
#pragma unroll
    for (int mi = 0; mi < 2; ++mi) {
#pragma unroll
      for (int rg = 0; rg < 4; ++rg) {
        int row = m0 + w * 32 + mi * 16 + lq * 4 + rg;
        if (row < M) {
          float v = acc[mi][ni][rg] + bias;
          H0f[(size_t)row * OUT + col] = v;
          H0b[(size_t)row * OUT + col] = f2bf(v);
        }
      }
    }
  }
}

// ---------------- graph prep: (dst, src-bucket) CSR ----------------
__global__ void count_deg8(const int* __restrict__ ei, int* __restrict__ cnt8, int E) {
  int e = blockIdx.x * 256 + threadIdx.x;
  if (e < E) {
    int s = ei[e], d = ei[E + e];
    atomicAdd(&cnt8[(size_t)d * 8 + (s >> 14)], 1);
  }
}

// dinv from bucketed offsets: deg(v) = offs8[(v+1)*8] - offs8[v*8]
__global__ void calc_dinv(const int* __restrict__ offs8, float* __restrict__ dinv, int n) {
  int v = blockIdx.x * 256 + threadIdx.x;
  if (v < n)
    dinv[v] = rsqrtf((float)(offs8[(size_t)(v + 1) * 8] - offs8[(size_t)v * 8]) + 1.0f);
}

// single-block exclusive scan of cnt[n] -> offs[n+1], cursor[n]; 8 elems/thread/iter
__global__ __launch_bounds__(1024) void scan_kernel(const int* __restrict__ cnt,
                                                    int* __restrict__ offs,
                                                    int* __restrict__ cursor, int n) {
  __shared__ int wsum[16];
  __shared__ int woff[16];
  __shared__ int carry_s;
  const int tid = threadIdx.x;
  const int lane = tid & 63, wid = tid >> 6;
  if (tid == 0) carry_s = 0;
  __syncthreads();
  for (int base = 0; base < n; base += 8192) {
    int i0 = base + tid * 8;
    int x[8];
#pragma unroll
    for (int j = 0; j < 8; ++j) x[j] = (i0 + j < n) ? cnt[i0 + j] : 0;
    int tsum = ((x[0] + x[1]) + (x[2] + x[3])) + ((x[4] + x[5]) + (x[6] + x[7]));
    int val = tsum;
#pragma unroll
    for (int d = 1; d < 64; d <<= 1) {
      int t = __shfl_up(val, d, 64);
      if (lane >= d) val += t;
    }
    if (lane == 63) wsum[wid] = val;
    __syncthreads();
    if (wid == 0) {
      int s = (lane < 16) ? wsum[lane] : 0;
      int sv = s;
#pragma unroll
      for (int d = 1; d < 16; d <<= 1) {
        int t = __shfl_up(sv, d, 64);
        if (lane >= d) sv += t;
      }
      if (lane < 16) woff[lane] = sv - s;
    }
    __syncthreads();
    int excl = carry_s + woff[wid] + (val - tsum);
#pragma unroll
    for (int j = 0; j < 8; ++j) {
      if (i0 + j < n) { offs[i0 + j] = excl; cursor[i0 + j] = excl; }
      excl += x[j];
    }
    __syncthreads();
    if (tid == 1023) carry_s = excl;
    __syncthreads();
  }
  if (tid == 0) offs[n] = carry_s;
}

// pack (src<<15) | fp16bits(w): src < 2^17, w > 0 so fp16 sign bit is dropped.
// scatter into (dst, src-bucket) segments via curs8.
__global__ void fill_csr(const int* __restrict__ ei, int* __restrict__ cursor8,
                         const float* __restrict__ dinv, unsigned int* __restrict__ csr,
                         int E) {
  int e = blockIdx.x * 256 + threadIdx.x;
  if (e < E) {
    int s = ei[e], d = ei[E + e];
    int p = atomicAdd(&cursor8[(size_t)d * 8 + (s >> 14)], 1);
    float w = dinv[s] * dinv[d];
    __half hw = __float2half(w);
    unsigned int hb = *reinterpret_cast<ushort*>(&hw);
    csr[p] = (((unsigned int)s) << 15) | hb;
  }
}

// ---------------- propagation: phase-major, grid-resident ----------------
// 6144 waves, each owning NPW=17 interleaved nodes (acc in regs). All waves
// sweep src-buckets p=0..7 in order: during phase p every gather on the GPU
// targets the 2MB hinb slice [p*16384, (p+1)*16384) -> L2-resident per XCD.
// Within a segment: 8 edges/iter, 2 edges per load (half-wave split), padded
// slots read row 0 (hot line, w=0).
template <bool WRITE_BF>
__global__ __launch_bounds__(256) void prop_step(const float* __restrict__ hinf,
                                                 const ushort* __restrict__ hinb,
                                                 float* __restrict__ houtf,
                                                 ushort* __restrict__ houtb,
                                                 const float* __restrict__ h0,
                                                 const int* __restrict__ offs8,
                                                 const unsigned int* __restrict__ csr,
                                                 const float* __restrict__ dinv,
                                                 int n, int nw) {
  const int wv = (blockIdx.x * 256 + threadIdx.x) >> 6;
  const int lane = threadIdx.x & 63;
  const unsigned int* hin32 = (const unsigned int*)hinb;
  const int c = lane & 31;       // feature pair index (features 2c, 2c+1)
  const int half = lane >> 5;    // 0: even-slot edges, 1: odd-slot edges
  float a0[NPW], a1[NPW];
#pragma unroll
  for (int i = 0; i < NPW; ++i) { a0[i] = 0.f; a1[i] = 0.f; }

  for (int p = 0; p < 8; ++p) {
#pragma unroll
    for (int i = 0; i < NPW; ++i) {
      int node = wv + i * nw;
      if (node < n) {
        int e0 = offs8[(size_t)node * 8 + p];
        int e1 = offs8[(size_t)node * 8 + p + 1];
        for (int base = e0; base < e1; base += 64) {
          int rem = e1 - base;
          unsigned int my = (lane < rem) ? csr[base + lane] : 0u;
          int cnt = rem < 64 ? rem : 64;
          for (int j = 0; j < cnt; j += 8) {
            unsigned int u0 = (unsigned int)__shfl((int)my, j + half, 64);
            unsigned int u1 = (unsigned int)__shfl((int)my, j + 2 + half, 64);
            unsigned int u2 = (unsigned int)__shfl((int)my, j + 4 + half, 64);
            unsigned int u3 = (unsigned int)__shfl((int)my, j + 6 + half, 64);
            unsigned int w0 = hin32[(size_t)(u0 >> 15) * 32 + c];
            unsigned int w1 = hin32[(size_t)(u1 >> 15) * 32 + c];
            unsigned int w2 = hin32[(size_t)(u2 >> 15) * 32 + c];
            unsigned int w3 = hin32[(size_t)(u3 >> 15) * 32 + c];
            float p0 = h15f(u0), p1 = h15f(u1), p2 = h15f(u2), p3 = h15f(u3);
            a0[i] = fmaf(p0, __uint_as_float(w0 << 16), a0[i]);
            a1[i] = fmaf(p0, __uint_as_float(w0 & 0xFFFF0000u), a1[i]);
            a0[i] = fmaf(p1, __uint_as_float(w1 << 16), a0[i]);
            a1[i] = fmaf(p1, __uint_as_float(w1 & 0xFFFF0000u), a1[i]);
            a0[i] = fmaf(p2, __uint_as_float(w2 << 16), a0[i]);
            a1[i] = fmaf(p2, __uint_as_float(w2 & 0xFFFF0000u), a1[i]);
            a0[i] = fmaf(p3, __uint_as_float(w3 << 16), a0[i]);
            a1[i] = fmaf(p3, __uint_as_float(w3 & 0xFFFF0000u), a1[i]);
          }
        }
      }
    }
  }

#pragma unroll
  for (int i = 0; i < NPW; ++i) {
    int node = wv + i * nw;
    if (node < n) {
      float s0 = a0[i] + __shfl_xor(a0[i], 32, 64);
      float s1 = a1[i] + __shfl_xor(a1[i], 32, 64);
      float dv = dinv[node];
      float2 hf = ((const float2*)hinf)[(size_t)node * 32 + c];
      float2 hh = ((const float2*)h0)[(size_t)node * 32 + c];
      float o0 = 0.9f * (s0 + dv * dv * hf.x) + 0.1f * hh.x;
      float o1 = 0.9f * (s1 + dv * dv * hf.y) + 0.1f * hh.y;
      if (half == 0) {
        float2 ov; ov.x = o0; ov.y = o1;
        ((float2*)houtf)[(size_t)node * 32 + c] = ov;
      } else if (WRITE_BF) {
        unsigned int pk = (unsigned int)f2bf(o0) | ((unsigned int)f2bf(o1) << 16);
        ((unsigned int*)houtb)[(size_t)node * 32 + c] = pk;
      }
    }
  }
}

extern "C" void kernel_launch(void* const* d_in, const int* in_sizes, int n_in,
                              void* d_out, int out_size, void* d_ws, size_t ws_size,
                              hipStream_t stream) {
  const float* X  = (const float*)d_in[0];  // [N,512] f32
  const int*   EI = (const int*)d_in[1];    // [2,E] int32
  const float* W1 = (const float*)d_in[2];  // [512,256] f32
  const float* b1 = (const float*)d_in[3];  // [256] f32
  const float* W2 = (const float*)d_in[4];  // [256,64] f32
  const float* b2 = (const float*)d_in[5];  // [64] f32
  float* out = (float*)d_out;               // [N,64] f32

  const int N = in_sizes[0] / IN;  // 100000
  const int E = in_sizes[1] / 2;   // 3200000

  char* ws = (char*)d_ws;
  size_t o = 0;
  auto alloc = [&](size_t b) {
    char* p = ws + o;
    o = (o + b + 255) & ~(size_t)255;
    return p;
  };
  float*  H0f  = (float*)alloc((size_t)N * OUT * 4);
  ushort* H0b  = (ushort*)alloc((size_t)N * OUT * 2);
  float*  hAf  = (float*)alloc((size_t)N * OUT * 4);
  ushort* hAb  = (ushort*)alloc((size_t)N * OUT * 2);
  float*  hBf  = (float*)alloc((size_t)N * OUT * 4);
  ushort* hBb  = (ushort*)alloc((size_t)N * OUT * 2);
  ushort* h1   = (ushort*)alloc((size_t)N * HID * 2);
  ushort* W1T  = (ushort*)alloc((size_t)IN * HID * 2);
  ushort* W2T  = (ushort*)alloc((size_t)HID * OUT * 2);
  int*    cnt8 = (int*)alloc((size_t)N * 8 * 4);
  int*    offs8 = (int*)alloc((size_t)(N * 8 + 1) * 4);
  int*    curs8 = (int*)alloc((size_t)N * 8 * 4);
  float*  dinv = (float*)alloc((size_t)N * 4);
  unsigned int* csr = (unsigned int*)alloc((size_t)E * 4);
  (void)ws_size; (void)n_in; (void)out_size;

  transpose_f32_bf16<<<(IN * HID + 255) / 256, 256, 0, stream>>>(W1, W1T, IN, HID);
  transpose_f32_bf16<<<(HID * OUT + 255) / 256, 256, 0, stream>>>(W2, W2T, HID, OUT);

  gemm1<<<dim3(HID / 128, (N + 127) / 128), 256, 0, stream>>>(X, W1T, b1, h1, N);
  gemm2<<<(N + 127) / 128, 256, 0, stream>>>(h1, W2T, b2, H0f, H0b, N);

  hipMemsetAsync(cnt8, 0, (size_t)N * 8 * 4, stream);
  count_deg8<<<(E + 255) / 256, 256, 0, stream>>>(EI, cnt8, E);
  scan_kernel<<<1, 1024, 0, stream>>>(cnt8, offs8, curs8, N * 8);
  calc_dinv<<<(N + 255) / 256, 256, 0, stream>>>(offs8, dinv, N);
  fill_csr<<<(E + 255) / 256, 256, 0, stream>>>(EI, curs8, dinv, csr, E);

  const int nwv = PGRID * 4;  // 6144 waves; NPW*nwv >= N
  prop_step<true><<<PGRID, 256, 0, stream>>>(H0f, H0b, hAf, hAb, H0f, offs8, csr, dinv, N, nwv);
  for (int i = 0; i < 4; ++i) {
    prop_step<true><<<PGRID, 256, 0, stream>>>(hAf, hAb, hBf, hBb, H0f, offs8, csr, dinv, N, nwv);
    prop_step<true><<<PGRID, 256, 0, stream>>>(hBf, hBb, hAf, hAb, H0f, offs8, csr, dinv, N, nwv);
  }
  prop_step<false><<<PGRID, 256, 0, stream>>>(hAf, hAb, out, nullptr, H0f, offs8, csr, dinv, N, nwv);
}

// Round 8
// 1278.150 us; speedup vs baseline: 3.3231x; 3.3231x over previous
//
#include <hip/hip_runtime.h>
#include <hip/hip_bf16.h>
#include <hip/hip_fp16.h>

// APPNP: h = MLP(x); 10x { h = 0.9 * (D^-1/2 (A+I) D^-1/2) h + 0.1 * h0 }
// fp32 in/out; GEMMs run bf16 MFMA with inline fp32->bf16 conversion.
// R4: byte-diet (bf16 mirror of h, 4B/edge CSR). R5/R8 CSR-build variants
//   REVERTED (atomic serialization / no XCD placement control): direct
//   scatter fill_csr (~160us, 197MB partial-line drain) is structural.
// R7 (GEMM reg-prefetch) REVERTED (VGPR/occupancy). R9: global_load_lds.
// R10: gemm1 2-phase double-buffer -> gemm1 out of top-5. KEEP.
// R11 REVERTED (both halves): (a) 800K single-block scan = 1077us latency
//   chain; (b) src-bucketed CSR -> ~4 edges/segment but 64-lane segment
//   reads = 16x CSR read amplification. Phase-major banding incompatible
//   with wave-per-node segments at degree 32.
// R12: R6 prop/CSR restored; scan replaced by 3-kernel multi-block scan
//   (per-block sums -> 25-partial scan -> per-block scan+offset). The old
//   single-block N=100K scan was a hidden ~135us (measured 1077us @ 800K).

typedef __bf16 bf16x8 __attribute__((ext_vector_type(8)));
typedef float f32x4 __attribute__((ext_vector_type(4)));

static constexpr int IN = 512, HID = 256, OUT = 64;
static constexpr int LDT = 40;   // LDS row stride (bf16 elems) for gemm2

static __device__ __forceinline__ ushort f2bf(float f) {
  __hip_bfloat16 b = __float2bfloat16(f);
  return *reinterpret_cast<ushort*>(&b);
}
static __device__ __forceinline__ float bf2f(ushort u) {
  unsigned int x = ((unsigned int)u) << 16;
  return __uint_as_float(x);
}
// decode low-15-bit fp16 (sign=0) weight
static __device__ __forceinline__ float h15f(unsigned int u) {
  ushort hb = (ushort)(u & 0x7FFFu);
  __half h = *reinterpret_cast<__half*>(&hb);
  return __half2float(h);
}

static __device__ __forceinline__ void gload16(const void* g, void* l) {
  __builtin_amdgcn_global_load_lds(
      (const __attribute__((address_space(1))) void*)g,
      (__attribute__((address_space(3))) void*)l, 16, 0, 0);
}

// ---------------- transpose fp32 [K][C] -> bf16 [C][K] ----------------
__global__ void transpose_f32_bf16(const float* __restrict__ in, ushort* __restrict__ out,
                                   int K, int C) {
  int idx = blockIdx.x * 256 + threadIdx.x;
  if (idx < K * C) {
    int n = idx / K, k = idx % K;
    out[idx] = f2bf(in[k * C + n]);
  }
}

// ---------------- GEMM1: h1 = relu(X @ W1 + b1) ----------------
// X [M,512] fp32, W1T [256,512] bf16, h1 [M,256] bf16. Tile 128x128x32.
// global_load_lds into double-buffered LDS; A fp32 in LDS (cvt at frag read).
__global__ __launch_bounds__(256) void gemm1(const float* __restrict__ X,
                                             const ushort* __restrict__ W1T,
                                             const float* __restrict__ b1,
                                             ushort* __restrict__ h1, int M) {
  __shared__ __align__(16) float As[2][128 * 32];   // 2x16KB fp32, chunk-swizzled
  __shared__ __align__(16) ushort Bs[2][128 * 32];  // 2x8KB bf16, chunk-swizzled
  const int tid = threadIdx.x;
  const int m0 = blockIdx.y * 128;
  const int n0 = blockIdx.x * 128;
  const int lane = tid & 63, w = tid >> 6;
  const int wr = w >> 1, wc = w & 1;
  const int lm = lane & 15, lq = lane >> 4;
  const int wbase = w * 64;

  auto STAGE = [&](int k0, int buf) {
#pragma unroll
    for (int i = 0; i < 4; ++i) {
      int idx = i * 256 + tid;
      int row = idx >> 3, ch = idx & 7;
      int gm = m0 + row; gm = gm < M ? gm : M - 1;
      int sch = ch ^ (row & 7);
      gload16(&X[(size_t)gm * IN + k0 + sch * 4], &As[buf][(i * 256 + wbase) * 4]);
    }
#pragma unroll
    for (int i = 0; i < 2; ++i) {
      int idx = i * 256 + tid;
      int row = idx >> 2, ch = idx & 3;
      int sch = ch ^ ((row ^ (row >> 2)) & 3);
      gload16(&W1T[(size_t)(n0 + row) * IN + k0 + sch * 8], &Bs[buf][(i * 256 + wbase) * 8]);
    }
  };

  f32x4 acc[4][4] = {};

  STAGE(0, 0);
  __syncthreads();

  int cur = 0;
  for (int k0 = 0; k0 < IN; k0 += 32) {
    if (k0 + 32 < IN) STAGE(k0 + 32, cur ^ 1);

    bf16x8 af[4], bq[4];
#pragma unroll
    for (int mi = 0; mi < 4; ++mi) {
      int r = wr * 64 + mi * 16 + lm;
      int k7 = r & 7;
      float4 x0 = *reinterpret_cast<const float4*>(&As[cur][r * 32 + ((2 * lq) ^ k7) * 4]);
      float4 x1 = *reinterpret_cast<const float4*>(&As[cur][r * 32 + ((2 * lq + 1) ^ k7) * 4]);
      union { ushort u[8]; bf16x8 v; } cv;
      cv.u[0] = f2bf(x0.x); cv.u[1] = f2bf(x0.y); cv.u[2] = f2bf(x0.z); cv.u[3] = f2bf(x0.w);
      cv.u[4] = f2bf(x1.x); cv.u[5] = f2bf(x1.y); cv.u[6] = f2bf(x1.z); cv.u[7] = f2bf(x1.w);
      af[mi] = cv.v;
    }
#pragma unroll
    for (int ni = 0; ni < 4; ++ni) {
      int r = wc * 64 + ni * 16 + lm;
      int key = (r ^ (r >> 2)) & 3;
      bq[ni] = *reinterpret_cast<const bf16x8*>(&Bs[cur][r * 32 + (lq ^ key) * 8]);
    }
#pragma unroll
    for (int mi = 0; mi < 4; ++mi)
#pragma unroll
      for (int ni = 0; ni < 4; ++ni)
        acc[mi][ni] = __builtin_amdgcn_mfma_f32_16x16x32_bf16(af[mi], bq[ni], acc[mi][ni], 0, 0, 0);

    __syncthreads();
    cur ^= 1;
  }

#pragma unroll
  for (int ni = 0; ni < 4; ++ni) {
    int col = n0 + wc * 64 + ni * 16 + lm;
    float bias = b1[col];
#pragma unroll
    for (int mi = 0; mi < 4; ++mi) {
#pragma unroll
      for (int rg = 0; rg < 4; ++rg) {
        int row = m0 + wr * 64 + mi * 16 + lq * 4 + rg;
        if (row < M) {
          float v = acc[mi][ni][rg] + bias;
          v = v > 0.f ? v : 0.f;
          h1[(size_t)row * HID + col] = f2bf(v);
        }
      }
    }
  }
}

// ---------------- GEMM2: H0 = h1 @ W2 + b2, fp32 + bf16 mirror out ----------------
__global__ __launch_bounds__(256) void gemm2(const ushort* __restrict__ h1,
                                             const ushort* __restrict__ W2T,
                                             const float* __restrict__ b2,
                                             float* __restrict__ H0f,
                                             ushort* __restrict__ H0b, int M) {
  __shared__ __align__(16) ushort As[128 * LDT];
  __shared__ __align__(16) ushort Bs[64 * LDT];
  const int tid = threadIdx.x;
  const int m0 = blockIdx.x * 128;
  const int lane = tid & 63, w = tid >> 6;
  const int lm = lane & 15, lq = lane >> 4;
  const int c = tid & 3, r = tid >> 2;

  f32x4 acc[2][4] = {};

  for (int k0 = 0; k0 < HID; k0 += 32) {
#pragma unroll
    for (int rr = 0; rr < 2; ++rr) {
      int m = r + rr * 64;
      int gm = m0 + m; gm = gm < M ? gm : M - 1;
      *reinterpret_cast<int4*>(&As[m * LDT + c * 8]) =
          *reinterpret_cast<const int4*>(&h1[(size_t)gm * HID + k0 + c * 8]);
    }
    *reinterpret_cast<int4*>(&Bs[r * LDT + c * 8]) =
        *reinterpret_cast<const int4*>(&W2T[(size_t)r * HID + k0 + c * 8]);
    __syncthreads();
    bf16x8 af[2], bq[4];
#pragma unroll
    for (int mi = 0; mi < 2; ++mi)
      af[mi] = *reinterpret_cast<const bf16x8*>(&As[(w * 32 + mi * 16 + lm) * LDT + lq * 8]);
#pragma unroll
    for (int ni = 0; ni < 4; ++ni)
      bq[ni] = *reinterpret_cast<const bf16x8*>(&Bs[(ni * 16 + lm) * LDT + lq * 8]);
#pragma unroll
    for (int mi = 0; mi < 2; ++mi)
#pragma unroll
      for (int ni = 0; ni < 4; ++ni)
        acc[mi][ni] = __builtin_amdgcn_mfma_f32_16x16x32_bf16(af[mi], bq[ni], acc[mi][ni], 0, 0, 0);
    __syncthreads();
  }

#pragma unroll
  for (int ni = 0; ni < 4; ++ni) {
    int col = ni * 16 + lm;
    float bias = b2[col];
#pragma unroll
    for (int mi = 0; mi < 2; ++mi) {
#pragma unroll
      for (int rg = 0; rg < 4; ++rg) {
        int row = m0 + w * 32 + mi * 16 + lq * 4 + rg;
        if (row < M) {
          float v = acc[mi][ni][rg] + bias;
          H0f[(size_t)row * OUT + col] = v;
          H0b[(size_t)row * OUT + col] = f2bf(v);
        }
      }
    }
  }
}

// ---------------- degree / dinv / multi-block scan / CSR ----------------
__global__ void count_deg(const int* __restrict__ ei, int* __restrict__ cnt, int E) {
  int e = blockIdx.x * 256 + threadIdx.x;
  if (e < E) atomicAdd(&cnt[ei[E + e]], 1);
}

__global__ void calc_dinv(const int* __restrict__ cnt, float* __restrict__ dinv, int n) {
  int v = blockIdx.x * 256 + threadIdx.x;
  if (v < n) dinv[v] = rsqrtf((float)cnt[v] + 1.0f);  // +1: self-loop
}

// scan phase 1: per-block (4096-elem tile) totals
__global__ __launch_bounds__(1024) void scan_p1(const int* __restrict__ cnt,
                                                int* __restrict__ bsum, int n) {
  __shared__ int wsum[16];
  const int tid = threadIdx.x, lane = tid & 63, wid = tid >> 6;
  int i0 = blockIdx.x * 4096 + tid * 4;
  int s = 0;
#pragma unroll
  for (int j = 0; j < 4; ++j) s += (i0 + j < n) ? cnt[i0 + j] : 0;
#pragma unroll
  for (int d = 1; d < 64; d <<= 1) s += __shfl_xor(s, d, 64);
  if (lane == 0) wsum[wid] = s;
  __syncthreads();
  if (tid == 0) {
    int t = 0;
#pragma unroll
    for (int i = 0; i < 16; ++i) t += wsum[i];
    bsum[blockIdx.x] = t;
  }
}

// scan phase 2: single-block exclusive scan of bsum[nb] (nb <= 1024)
__global__ __launch_bounds__(1024) void scan_p2(int* __restrict__ bsum, int nb) {
  __shared__ int wsum[16];
  __shared__ int woff[16];
  const int tid = threadIdx.x, lane = tid & 63, wid = tid >> 6;
  int x = (tid < nb) ? bsum[tid] : 0;
  int val = x;
#pragma unroll
  for (int d = 1; d < 64; d <<= 1) {
    int t = __shfl_up(val, d, 64);
    if (lane >= d) val += t;
  }
  if (lane == 63) wsum[wid] = val;
  __syncthreads();
  if (wid == 0) {
    int s = (lane < 16) ? wsum[lane] : 0;
    int sv = s;
#pragma unroll
    for (int d = 1; d < 16; d <<= 1) {
      int t = __shfl_up(sv, d, 64);
      if (lane >= d) sv += t;
    }
    if (lane < 16) woff[lane] = sv - s;
  }
  __syncthreads();
  if (tid < nb) bsum[tid] = woff[wid] + (val - x);
}

// scan phase 3: per-block scan + block offset -> offs, cursor; last writes offs[n]
__global__ __launch_bounds__(1024) void scan_p3(const int* __restrict__ cnt,
                                                const int* __restrict__ bsum,
                                                int* __restrict__ offs,
                                                int* __restrict__ cursor, int n) {
  __shared__ int wsum[16];
  __shared__ int woff[16];
  const int tid = threadIdx.x, lane = tid & 63, wid = tid >> 6;
  int i0 = blockIdx.x * 4096 + tid * 4;
  int x[4];
#pragma unroll
  for (int j = 0; j < 4; ++j) x[j] = (i0 + j < n) ? cnt[i0 + j] : 0;
  int tsum = x[0] + x[1] + x[2] + x[3];
  int val = tsum;
#pragma unroll
  for (int d = 1; d < 64; d <<= 1) {
    int t = __shfl_up(val, d, 64);
    if (lane >= d) val += t;
  }
  if (lane == 63) wsum[wid] = val;
  __syncthreads();
  if (wid == 0) {
    int s = (lane < 16) ? wsum[lane] : 0;
    int sv = s;
#pragma unroll
    for (int d = 1; d < 16; d <<= 1) {
      int t = __shfl_up(sv, d, 64);
      if (lane >= d) sv += t;
    }
    if (lane < 16) woff[lane] = sv - s;
  }
  __syncthreads();
  int excl = bsum[blockIdx.x] + woff[wid] + (val - tsum);
#pragma unroll
  for (int j = 0; j < 4; ++j) {
    if (i0 + j < n) { offs[i0 + j] = excl; cursor[i0 + j] = excl; }
    excl += x[j];
  }
  if (i0 < n && i0 + 4 >= n) offs[n] = excl;  // thread owning the last element
}

// pack (src<<15) | fp16bits(w): src < 2^17, w > 0 so fp16 sign bit is dropped
__global__ void fill_csr(const int* __restrict__ ei, int* __restrict__ cursor,
                         const float* __restrict__ dinv, unsigned int* __restrict__ csr,
                         int E) {
  int e = blockIdx.x * 256 + threadIdx.x;
  if (e < E) {
    int s = ei[e], d = ei[E + e];
    int p = atomicAdd(&cursor[d], 1);
    float w = dinv[s] * dinv[d];
    __half hw = __float2half(w);
    unsigned int hb = *reinterpret_cast<ushort*>(&hw);
    csr[p] = (((unsigned int)s) << 15) | hb;
  }
}

// ---------------- propagation: one wave per node ----------------
// Lane l batch-fetches csr[base+l] (256B coalesced per 64 edges), shfl-broadcasts.
// 2 edges per load: lanes 0-31 read edge (j+2k) row as uint (features 2c,2c+1),
// lanes 32-63 read edge (j+2k+1). 16 loads in flight = 32 edges. Even/odd-edge
// partial sums combined with shfl_xor(32); fp32 write by lanes<32, bf16 by lanes>=32.
template <bool WRITE_BF>
__global__ __launch_bounds__(256) void prop_step(const float* __restrict__ hinf,
                                                 const ushort* __restrict__ hinb,
                                                 float* __restrict__ houtf,
                                                 ushort* __restrict__ houtb,
                                                 const float* __restrict__ h0,
                                                 const int* __restrict__ offs,
                                                 const unsigned int* __restrict__ csr,
                                                 const float* __restrict__ dinv, int n) {
  int gw = (blockIdx.x * 256 + threadIdx.x) >> 6;
  int lane = threadIdx.x & 63;
  if (gw >= n) return;
  const unsigned int* hin32 = (const unsigned int*)hinb;
  const int c = lane & 31;       // feature pair index (features 2c, 2c+1)
  const int half = lane >> 5;    // 0: even-slot edges, 1: odd-slot edges
  float alo[8], ahi[8];
#pragma unroll
  for (int k = 0; k < 8; ++k) { alo[k] = 0.f; ahi[k] = 0.f; }
  int e0 = offs[gw], e1 = offs[gw + 1];
  for (int base = e0; base < e1; base += 64) {
    int rem = e1 - base;
    // padded lanes: u=0 -> src=0, w=+0 (row 0 is valid; contribution is 0)
    unsigned int my = (lane < rem) ? csr[base + lane] : 0u;
    int cnt = rem < 64 ? rem : 64;
    int cnt32 = (cnt + 31) & ~31;
    for (int j = 0; j < cnt32; j += 32) {
      unsigned int u[16];
#pragma unroll
      for (int k = 0; k < 16; ++k)
        u[k] = (unsigned int)__shfl((int)my, j + 2 * k + half);
      unsigned int v[16];
#pragma unroll
      for (int k = 0; k < 16; ++k)
        v[k] = hin32[(size_t)(u[k] >> 15) * 32 + c];
#pragma unroll
      for (int k = 0; k < 16; ++k) {
        float w = h15f(u[k]);
        float f0 = __uint_as_float(v[k] << 16);
        float f1 = __uint_as_float(v[k] & 0xFFFF0000u);
        alo[k & 7] = fmaf(w, f0, alo[k & 7]);
        ahi[k & 7] = fmaf(w, f1, ahi[k & 7]);
      }
    }
  }
  float a0 = ((alo[0] + alo[1]) + (alo[2] + alo[3])) + ((alo[4] + alo[5]) + (alo[6] + alo[7]));
  float a1 = ((ahi[0] + ahi[1]) + (ahi[2] + ahi[3])) + ((ahi[4] + ahi[5]) + (ahi[6] + ahi[7]));
  // combine even/odd-edge halves (partner lane holds same features, other parity)
  a0 += __shfl_xor(a0, 32, 64);
  a1 += __shfl_xor(a1, 32, 64);
  float dv = dinv[gw];
  float2 hf = ((const float2*)hinf)[(size_t)gw * 32 + c];
  float2 h0f = ((const float2*)h0)[(size_t)gw * 32 + c];
  float o0 = 0.9f * (a0 + dv * dv * hf.x) + 0.1f * h0f.x;
  float o1 = 0.9f * (a1 + dv * dv * hf.y) + 0.1f * h0f.y;
  if (half == 0) {
    float2 ov; ov.x = o0; ov.y = o1;
    ((float2*)houtf)[(size_t)gw * 32 + c] = ov;
  } else if (WRITE_BF) {
    unsigned int pk = (unsigned int)f2bf(o0) | ((unsigned int)f2bf(o1) << 16);
    ((unsigned int*)houtb)[(size_t)gw * 32 + c] = pk;
  }
}

extern "C" void kernel_launch(void* const* d_in, const int* in_sizes, int n_in,
                              void* d_out, int out_size, void* d_ws, size_t ws_size,
                              hipStream_t stream) {
  const float* X  = (const float*)d_in[0];  // [N,512] f32
  const int*   EI = (const int*)d_in[1];    // [2,E] int32
  const float* W1 = (const float*)d_in[2];  // [512,256] f32
  const float* b1 = (const float*)d_in[3];  // [256] f32
  const float* W2 = (const float*)d_in[4];  // [256,64] f32
  const float* b2 = (const float*)d_in[5];  // [64] f32
  float* out = (float*)d_out;               // [N,64] f32

  const int N = in_sizes[0] / IN;  // 100000
  const int E = in_sizes[1] / 2;   // 3200000

  char* ws = (char*)d_ws;
  size_t o = 0;
  auto alloc = [&](size_t b) {
    char* p = ws + o;
    o = (o + b + 255) & ~(size_t)255;
    return p;
  };
  float*  H0f  = (float*)alloc((size_t)N * OUT * 4);
  ushort* H0b  = (ushort*)alloc((size_t)N * OUT * 2);
  float*  hAf  = (float*)alloc((size_t)N * OUT * 4);
  ushort* hAb  = (ushort*)alloc((size_t)N * OUT * 2);
  float*  hBf  = (float*)alloc((size_t)N * OUT * 4);
  ushort* hBb  = (ushort*)alloc((size_t)N * OUT * 2);
  ushort* h1   = (ushort*)alloc((size_t)N * HID * 2);
  ushort* W1T  = (ushort*)alloc((size_t)IN * HID * 2);
  ushort* W2T  = (ushort*)alloc((size_t)HID * OUT * 2);
  int*    cnt  = (int*)alloc((size_t)N * 4);
  int*    offs = (int*)alloc((size_t)(N + 1) * 4);
  int*    curs = (int*)alloc((size_t)N * 4);
  int*    bsum = (int*)alloc((size_t)1024 * 4);
  float*  dinv = (float*)alloc((size_t)N * 4);
  unsigned int* csr = (unsigned int*)alloc((size_t)E * 4);
  (void)ws_size; (void)n_in; (void)out_size;

  transpose_f32_bf16<<<(IN * HID + 255) / 256, 256, 0, stream>>>(W1, W1T, IN, HID);
  transpose_f32_bf16<<<(HID * OUT + 255) / 256, 256, 0, stream>>>(W2, W2T, HID, OUT);

  gemm1<<<dim3(HID / 128, (N + 127) / 128), 256, 0, stream>>>(X, W1T, b1, h1, N);
  gemm2<<<(N + 127) / 128, 256, 0, stream>>>(h1, W2T, b2, H0f, H0b, N);

  hipMemsetAsync(cnt, 0, (size_t)N * 4, stream);
  count_deg<<<(E + 255) / 256, 256, 0, stream>>>(EI, cnt, E);
  calc_dinv<<<(N + 255) / 256, 256, 0, stream>>>(cnt, dinv, N);
  const int NB = (N + 4095) / 4096;  // 25
  scan_p1<<<NB, 1024, 0, stream>>>(cnt, bsum, N);
  scan_p2<<<1, 1024, 0, stream>>>(bsum, NB);
  scan_p3<<<NB, 1024, 0, stream>>>(cnt, bsum, offs, curs, N);
  fill_csr<<<(E + 255) / 256, 256, 0, stream>>>(EI, curs, dinv, csr, E);

  const int pgrid = (N * OUT + 255) / 256;  // one wave per node
  prop_step<true><<<pgrid, 256, 0, stream>>>(H0f, H0b, hAf, hAb, H0f, offs, csr, dinv, N);
  for (int i = 0; i < 4; ++i) {
    prop_step<true><<<pgrid, 256, 0, stream>>>(hAf, hAb, hBf, hBb, H0f, offs, csr, dinv, N);
    prop_step<true><<<pgrid, 256, 0, stream>>>(hBf, hBb, hAf, hAb, H0f, offs, csr, dinv, N);
  }
  prop_step<false><<<pgrid, 256, 0, stream>>>(hAf, hAb, out, nullptr, H0f, offs, csr, dinv, N);
}

// Round 9
// 1223.079 us; speedup vs baseline: 3.4728x; 1.0450x over previous
//
#include <hip/hip_runtime.h>
#include <hip/hip_bf16.h>
#include <hip/hip_fp16.h>

// APPNP: h = MLP(x); 10x { h = 0.9 * (D^-1/2 (A+I) D^-1/2) h + 0.1 * h0 }
// fp32 in/out; GEMMs run bf16 MFMA with inline fp32->bf16 conversion.
// R4: byte-diet (bf16 mirror of h, 4B/edge CSR). R5/R8 CSR-build variants
//   REVERTED (atomic serialization / no XCD placement control): direct
//   scatter fill_csr (~160us, 197MB partial-line drain) is structural.
// R7 (GEMM reg-prefetch) REVERTED (VGPR/occupancy). R9: global_load_lds.
// R10: gemm1 2-phase double-buffer -> gemm1 out of top-5. KEEP.
// R11 REVERTED: single-block 800K scan (1077us latency chain) + bucketed
//   CSR (16x csr read amp at degree-4 segments).
// R12: 3-kernel multi-block scan -> ~70us recovered. 1278us best.
// R13: h state bf16-ONLY between prop steps. The fp32 h mirror protected
//   only the self-loop term (weight dv^2~0.03); its bf16 rounding is ~20x
//   below the existing neighbor-rounding error. Teleport h0 stays fp32.
//   Per-step streams drop 102->51MB (drop hinf read + houtf write);
//   final step writes fp32 out from the fp32 accumulator.

typedef __bf16 bf16x8 __attribute__((ext_vector_type(8)));
typedef float f32x4 __attribute__((ext_vector_type(4)));

static constexpr int IN = 512, HID = 256, OUT = 64;
static constexpr int LDT = 40;   // LDS row stride (bf16 elems) for gemm2

static __device__ __forceinline__ ushort f2bf(float f) {
  __hip_bfloat16 b = __float2bfloat16(f);
  return *reinterpret_cast<ushort*>(&b);
}
static __device__ __forceinline__ float bf2f(ushort u) {
  unsigned int x = ((unsigned int)u) << 16;
  return __uint_as_float(x);
}
// decode low-15-bit fp16 (sign=0) weight
static __device__ __forceinline__ float h15f(unsigned int u) {
  ushort hb = (ushort)(u & 0x7FFFu);
  __half h = *reinterpret_cast<__half*>(&hb);
  return __half2float(h);
}

static __device__ __forceinline__ void gload16(const void* g, void* l) {
  __builtin_amdgcn_global_load_lds(
      (const __attribute__((address_space(1))) void*)g,
      (__attribute__((address_space(3))) void*)l, 16, 0, 0);
}

// ---------------- transpose fp32 [K][C] -> bf16 [C][K] ----------------
__global__ void transpose_f32_bf16(const float* __restrict__ in, ushort* __restrict__ out,
                                   int K, int C) {
  int idx = blockIdx.x * 256 + threadIdx.x;
  if (idx < K * C) {
    int n = idx / K, k = idx % K;
    out[idx] = f2bf(in[k * C + n]);
  }
}

// ---------------- GEMM1: h1 = relu(X @ W1 + b1) ----------------
// X [M,512] fp32, W1T [256,512] bf16, h1 [M,256] bf16. Tile 128x128x32.
// global_load_lds into double-buffered LDS; A fp32 in LDS (cvt at frag read).
__global__ __launch_bounds__(256) void gemm1(const float* __restrict__ X,
                                             const ushort* __restrict__ W1T,
                                             const float* __restrict__ b1,
                                             ushort* __restrict__ h1, int M) {
  __shared__ __align__(16) float As[2][128 * 32];   // 2x16KB fp32, chunk-swizzled
  __shared__ __align__(16) ushort Bs[2][128 * 32];  // 2x8KB bf16, chunk-swizzled
  const int tid = threadIdx.x;
  const int m0 = blockIdx.y * 128;
  const int n0 = blockIdx.x * 128;
  const int lane = tid & 63, w = tid >> 6;
  const int wr = w >> 1, wc = w & 1;
  const int lm = lane & 15, lq = lane >> 4;
  const int wbase = w * 64;

  auto STAGE = [&](int k0, int buf) {
#pragma unroll
    for (int i = 0; i < 4; ++i) {
      int idx = i * 256 + tid;
      int row = idx >> 3, ch = idx & 7;
      int gm = m0 + row; gm = gm < M ? gm : M - 1;
      int sch = ch ^ (row & 7);
      gload16(&X[(size_t)gm * IN + k0 + sch * 4], &As[buf][(i * 256 + wbase) * 4]);
    }
#pragma unroll
    for (int i = 0; i < 2; ++i) {
      int idx = i * 256 + tid;
      int row = idx >> 2, ch = idx & 3;
      int sch = ch ^ ((row ^ (row >> 2)) & 3);
      gload16(&W1T[(size_t)(n0 + row) * IN + k0 + sch * 8], &Bs[buf][(i * 256 + wbase) * 8]);
    }
  };

  f32x4 acc[4][4] = {};

  STAGE(0, 0);
  __syncthreads();

  int cur = 0;
  for (int k0 = 0; k0 < IN; k0 += 32) {
    if (k0 + 32 < IN) STAGE(k0 + 32, cur ^ 1);

    bf16x8 af[4], bq[4];
#pragma unroll
    for (int mi = 0; mi < 4; ++mi) {
      int r = wr * 64 + mi * 16 + lm;
      int k7 = r & 7;
      float4 x0 = *reinterpret_cast<const float4*>(&As[cur][r * 32 + ((2 * lq) ^ k7) * 4]);
      float4 x1 = *reinterpret_cast<const float4*>(&As[cur][r * 32 + ((2 * lq + 1) ^ k7) * 4]);
      union { ushort u[8]; bf16x8 v; } cv;
      cv.u[0] = f2bf(x0.x); cv.u[1] = f2bf(x0.y); cv.u[2] = f2bf(x0.z); cv.u[3] = f2bf(x0.w);
      cv.u[4] = f2bf(x1.x); cv.u[5] = f2bf(x1.y); cv.u[6] = f2bf(x1.z); cv.u[7] = f2bf(x1.w);
      af[mi] = cv.v;
    }
#pragma unroll
    for (int ni = 0; ni < 4; ++ni) {
      int r = wc * 64 + ni * 16 + lm;
      int key = (r ^ (r >> 2)) & 3;
      bq[ni] = *reinterpret_cast<const bf16x8*>(&Bs[cur][r * 32 + (lq ^ key) * 8]);
    }
#pragma unroll
    for (int mi = 0; mi < 4; ++mi)
#pragma unroll
      for (int ni = 0; ni < 4; ++ni)
        acc[mi][ni] = __builtin_amdgcn_mfma_f32_16x16x32_bf16(af[mi], bq[ni], acc[mi][ni], 0, 0, 0);

    __syncthreads();
    cur ^= 1;
  }

#pragma unroll
  for (int ni = 0; ni < 4; ++ni) {
    int col = n0 + wc * 64 + ni * 16 + lm;
    float bias = b1[col];
#pragma unroll
    for (int mi = 0; mi < 4; ++mi) {
#pragma unroll
      for (int rg = 0; rg < 4; ++rg) {
        int row = m0 + wr * 64 + mi * 16 + lq * 4 + rg;
        if (row < M) {
          float v = acc[mi][ni][rg] + bias;
          v = v > 0.f ? v : 0.f;
          h1[(size_t)row * HID + col] = f2bf(v);
        }
      }
    }
  }
}

// ---------------- GEMM2: H0 = h1 @ W2 + b2, fp32 + bf16 mirror out ----------------
__global__ __launch_bounds__(256) void gemm2(const ushort* __restrict__ h1,
                                             const ushort* __restrict__ W2T,
                                             const float* __restrict__ b2,
                                             float* __restrict__ H0f,
                                             ushort* __restrict__ H0b, int M) {
  __shared__ __align__(16) ushort As[128 * LDT];
  __shared__ __align__(16) ushort Bs[64 * LDT];
  const int tid = threadIdx.x;
  const int m0 = blockIdx.x * 128;
  const int lane = tid & 63, w = tid >> 6;
  const int lm = lane & 15, lq = lane >> 4;
  const int c = tid & 3, r = tid >> 2;

  f32x4 acc[2][4] = {};

  for (int k0 = 0; k0 < HID; k0 += 32) {
#pragma unroll
    for (int rr = 0; rr < 2; ++rr) {
      int m = r + rr * 64;
      int gm = m0 + m; gm = gm < M ? gm : M - 1;
      *reinterpret_cast<int4*>(&As[m * LDT + c * 8]) =
          *reinterpret_cast<const int4*>(&h1[(size_t)gm * HID + k0 + c * 8]);
    }
    *reinterpret_cast<int4*>(&Bs[r * LDT + c * 8]) =
        *reinterpret_cast<const int4*>(&W2T[(size_t)r * HID + k0 + c * 8]);
    __syncthreads();
    bf16x8 af[2], bq[4];
#pragma unroll
    for (int mi = 0; mi < 2; ++mi)
      af[mi] = *reinterpret_cast<const bf16x8*>(&As[(w * 32 + mi * 16 + lm) * LDT + lq * 8]);
#pragma unroll
    for (int ni = 0; ni < 4; ++ni)
      bq[ni] = *reinterpret_cast<const bf16x8*>(&Bs[(ni * 16 + lm) * LDT + lq * 8]);
#pragma unroll
    for (int mi = 0; mi < 2; ++mi)
#pragma unroll
      for (int ni = 0; ni < 4; ++ni)
        acc[mi][ni] = __builtin_amdgcn_mfma_f32_16x16x32_bf16(af[mi], bq[ni], acc[mi][ni], 0, 0, 0);
    __syncthreads();
  }

#pragma unroll
  for (int ni = 0; ni < 4; ++ni) {
    int col = ni * 16 + lm;
    float bias = b2[col];
#pragma unroll
    for (int mi = 0; mi < 2; ++mi) {
#pragma unroll
      for (int rg = 0; rg < 4; ++rg) {
        int row = m0 + w * 32 + mi * 16 + lq * 4 + rg;
        if (row < M) {
          float v = acc[mi][ni][rg] + bias;
          H0f[(size_t)row * OUT + col] = v;
          H0b[(size_t)row * OUT + col] = f2bf(v);
        }
      }
    }
  }
}

// ---------------- degree / dinv / multi-block scan / CSR ----------------
__global__ void count_deg(const int* __restrict__ ei, int* __restrict__ cnt, int E) {
  int e = blockIdx.x * 256 + threadIdx.x;
  if (e < E) atomicAdd(&cnt[ei[E + e]], 1);
}

__global__ void calc_dinv(const int* __restrict__ cnt, float* __restrict__ dinv, int n) {
  int v = blockIdx.x * 256 + threadIdx.x;
  if (v < n) dinv[v] = rsqrtf((float)cnt[v] + 1.0f);  // +1: self-loop
}

// scan phase 1: per-block (4096-elem tile) totals
__global__ __launch_bounds__(1024) void scan_p1(const int* __restrict__ cnt,
                                                int* __restrict__ bsum, int n) {
  __shared__ int wsum[16];
  const int tid = threadIdx.x, lane = tid & 63, wid = tid >> 6;
  int i0 = blockIdx.x * 4096 + tid * 4;
  int s = 0;
#pragma unroll
  for (int j = 0; j < 4; ++j) s += (i0 + j < n) ? cnt[i0 + j] : 0;
#pragma unroll
  for (int d = 1; d < 64; d <<= 1) s += __shfl_xor(s, d, 64);
  if (lane == 0) wsum[wid] = s;
  __syncthreads();
  if (tid == 0) {
    int t = 0;
#pragma unroll
    for (int i = 0; i < 16; ++i) t += wsum[i];
    bsum[blockIdx.x] = t;
  }
}

// scan phase 2: single-block exclusive scan of bsum[nb] (nb <= 1024)
__global__ __launch_bounds__(1024) void scan_p2(int* __restrict__ bsum, int nb) {
  __shared__ int wsum[16];
  __shared__ int woff[16];
  const int tid = threadIdx.x, lane = tid & 63, wid = tid >> 6;
  int x = (tid < nb) ? bsum[tid] : 0;
  int val = x;
#pragma unroll
  for (int d = 1; d < 64; d <<= 1) {
    int t = __shfl_up(val, d, 64);
    if (lane >= d) val += t;
  }
  if (lane == 63) wsum[wid] = val;
  __syncthreads();
  if (wid == 0) {
    int s = (lane < 16) ? wsum[lane] : 0;
    int sv = s;
#pragma unroll
    for (int d = 1; d < 16; d <<= 1) {
      int t = __shfl_up(sv, d, 64);
      if (lane >= d) sv += t;
    }
    if (lane < 16) woff[lane] = sv - s;
  }
  __syncthreads();
  if (tid < nb) bsum[tid] = woff[wid] + (val - x);
}

// scan phase 3: per-block scan + block offset -> offs, cursor; last writes offs[n]
__global__ __launch_bounds__(1024) void scan_p3(const int* __restrict__ cnt,
                                                const int* __restrict__ bsum,
                                                int* __restrict__ offs,
                                                int* __restrict__ cursor, int n) {
  __shared__ int wsum[16];
  __shared__ int woff[16];
  const int tid = threadIdx.x, lane = tid & 63, wid = tid >> 6;
  int i0 = blockIdx.x * 4096 + tid * 4;
  int x[4];
#pragma unroll
  for (int j = 0; j < 4; ++j) x[j] = (i0 + j < n) ? cnt[i0 + j] : 0;
  int tsum = x[0] + x[1] + x[2] + x[3];
  int val = tsum;
#pragma unroll
  for (int d = 1; d < 64; d <<= 1) {
    int t = __shfl_up(val, d, 64);
    if (lane >= d) val += t;
  }
  if (lane == 63) wsum[wid] = val;
  __syncthreads();
  if (wid == 0) {
    int s = (lane < 16) ? wsum[lane] : 0;
    int sv = s;
#pragma unroll
    for (int d = 1; d < 16; d <<= 1) {
      int t = __shfl_up(sv, d, 64);
      if (lane >= d) sv += t;
    }
    if (lane < 16) woff[lane] = sv - s;
  }
  __syncthreads();
  int excl = bsum[blockIdx.x] + woff[wid] + (val - tsum);
#pragma unroll
  for (int j = 0; j < 4; ++j) {
    if (i0 + j < n) { offs[i0 + j] = excl; cursor[i0 + j] = excl; }
    excl += x[j];
  }
  if (i0 < n && i0 + 4 >= n) offs[n] = excl;  // thread owning the last element
}

// pack (src<<15) | fp16bits(w): src < 2^17, w > 0 so fp16 sign bit is dropped
__global__ void fill_csr(const int* __restrict__ ei, int* __restrict__ cursor,
                         const float* __restrict__ dinv, unsigned int* __restrict__ csr,
                         int E) {
  int e = blockIdx.x * 256 + threadIdx.x;
  if (e < E) {
    int s = ei[e], d = ei[E + e];
    int p = atomicAdd(&cursor[d], 1);
    float w = dinv[s] * dinv[d];
    __half hw = __float2half(w);
    unsigned int hb = *reinterpret_cast<ushort*>(&hw);
    csr[p] = (((unsigned int)s) << 15) | hb;
  }
}

// ---------------- propagation: one wave per node, bf16 state only ----------------
// Lane l batch-fetches csr[base+l] (256B coalesced per 64 edges), shfl-broadcasts.
// 2 edges per load: lanes 0-31 read edge (j+2k) row as uint (features 2c,2c+1),
// lanes 32-63 read edge (j+2k+1). Even/odd-edge partial sums combined with
// shfl_xor(32). Self-loop read from the bf16 state (error ~20x below existing
// neighbor rounding); teleport h0 stays fp32. Intermediate: bf16 write only
// (half 1); FINAL: fp32 out write only (half 0).
template <bool FINAL>
__global__ __launch_bounds__(256) void prop_step(const ushort* __restrict__ hinb,
                                                 ushort* __restrict__ houtb,
                                                 float* __restrict__ out,
                                                 const float* __restrict__ h0,
                                                 const int* __restrict__ offs,
                                                 const unsigned int* __restrict__ csr,
                                                 const float* __restrict__ dinv, int n) {
  int gw = (blockIdx.x * 256 + threadIdx.x) >> 6;
  int lane = threadIdx.x & 63;
  if (gw >= n) return;
  const unsigned int* hin32 = (const unsigned int*)hinb;
  const int c = lane & 31;       // feature pair index (features 2c, 2c+1)
  const int half = lane >> 5;    // 0: even-slot edges, 1: odd-slot edges
  float alo[8], ahi[8];
#pragma unroll
  for (int k = 0; k < 8; ++k) { alo[k] = 0.f; ahi[k] = 0.f; }
  int e0 = offs[gw], e1 = offs[gw + 1];
  for (int base = e0; base < e1; base += 64) {
    int rem = e1 - base;
    // padded lanes: u=0 -> src=0, w=+0 (row 0 is valid; contribution is 0)
    unsigned int my = (lane < rem) ? csr[base + lane] : 0u;
    int cnt = rem < 64 ? rem : 64;
    int cnt32 = (cnt + 31) & ~31;
    for (int j = 0; j < cnt32; j += 32) {
      unsigned int u[16];
#pragma unroll
      for (int k = 0; k < 16; ++k)
        u[k] = (unsigned int)__shfl((int)my, j + 2 * k + half);
      unsigned int v[16];
#pragma unroll
      for (int k = 0; k < 16; ++k)
        v[k] = hin32[(size_t)(u[k] >> 15) * 32 + c];
#pragma unroll
      for (int k = 0; k < 16; ++k) {
        float w = h15f(u[k]);
        float f0 = __uint_as_float(v[k] << 16);
        float f1 = __uint_as_float(v[k] & 0xFFFF0000u);
        alo[k & 7] = fmaf(w, f0, alo[k & 7]);
        ahi[k & 7] = fmaf(w, f1, ahi[k & 7]);
      }
    }
  }
  float a0 = ((alo[0] + alo[1]) + (alo[2] + alo[3])) + ((alo[4] + alo[5]) + (alo[6] + alo[7]));
  float a1 = ((ahi[0] + ahi[1]) + (ahi[2] + ahi[3])) + ((ahi[4] + ahi[5]) + (ahi[6] + ahi[7]));
  // combine even/odd-edge halves (partner lane holds same features, other parity)
  a0 += __shfl_xor(a0, 32, 64);
  a1 += __shfl_xor(a1, 32, 64);
  float dv = dinv[gw];
  unsigned int sv = hin32[(size_t)gw * 32 + c];  // self row (bf16 state)
  float sx = __uint_as_float(sv << 16);
  float sy = __uint_as_float(sv & 0xFFFF0000u);
  float2 h0f = ((const float2*)h0)[(size_t)gw * 32 + c];
  float o0 = 0.9f * (a0 + dv * dv * sx) + 0.1f * h0f.x;
  float o1 = 0.9f * (a1 + dv * dv * sy) + 0.1f * h0f.y;
  if (FINAL) {
    if (half == 0) {
      float2 ov; ov.x = o0; ov.y = o1;
      ((float2*)out)[(size_t)gw * 32 + c] = ov;
    }
  } else {
    if (half == 1) {
      unsigned int pk = (unsigned int)f2bf(o0) | ((unsigned int)f2bf(o1) << 16);
      ((unsigned int*)houtb)[(size_t)gw * 32 + c] = pk;
    }
  }
}

extern "C" void kernel_launch(void* const* d_in, const int* in_sizes, int n_in,
                              void* d_out, int out_size, void* d_ws, size_t ws_size,
                              hipStream_t stream) {
  const float* X  = (const float*)d_in[0];  // [N,512] f32
  const int*   EI = (const int*)d_in[1];    // [2,E] int32
  const float* W1 = (const float*)d_in[2];  // [512,256] f32
  const float* b1 = (const float*)d_in[3];  // [256] f32
  const float* W2 = (const float*)d_in[4];  // [256,64] f32
  const float* b2 = (const float*)d_in[5];  // [64] f32
  float* out = (float*)d_out;               // [N,64] f32

  const int N = in_sizes[0] / IN;  // 100000
  const int E = in_sizes[1] / 2;   // 3200000

  char* ws = (char*)d_ws;
  size_t o = 0;
  auto alloc = [&](size_t b) {
    char* p = ws + o;
    o = (o + b + 255) & ~(size_t)255;
    return p;
  };
  float*  H0f  = (float*)alloc((size_t)N * OUT * 4);
  ushort* H0b  = (ushort*)alloc((size_t)N * OUT * 2);
  ushort* hAb  = (ushort*)alloc((size_t)N * OUT * 2);
  ushort* hBb  = (ushort*)alloc((size_t)N * OUT * 2);
  ushort* h1   = (ushort*)alloc((size_t)N * HID * 2);
  ushort* W1T  = (ushort*)alloc((size_t)IN * HID * 2);
  ushort* W2T  = (ushort*)alloc((size_t)HID * OUT * 2);
  int*    cnt  = (int*)alloc((size_t)N * 4);
  int*    offs = (int*)alloc((size_t)(N + 1) * 4);
  int*    curs = (int*)alloc((size_t)N * 4);
  int*    bsum = (int*)alloc((size_t)1024 * 4);
  float*  dinv = (float*)alloc((size_t)N * 4);
  unsigned int* csr = (unsigned int*)alloc((size_t)E * 4);
  (void)ws_size; (void)n_in; (void)out_size;

  transpose_f32_bf16<<<(IN * HID + 255) / 256, 256, 0, stream>>>(W1, W1T, IN, HID);
  transpose_f32_bf16<<<(HID * OUT + 255) / 256, 256, 0, stream>>>(W2, W2T, HID, OUT);

  gemm1<<<dim3(HID / 128, (N + 127) / 128), 256, 0, stream>>>(X, W1T, b1, h1, N);
  gemm2<<<(N + 127) / 128, 256, 0, stream>>>(h1, W2T, b2, H0f, H0b, N);

  hipMemsetAsync(cnt, 0, (size_t)N * 4, stream);
  count_deg<<<(E + 255) / 256, 256, 0, stream>>>(EI, cnt, E);
  calc_dinv<<<(N + 255) / 256, 256, 0, stream>>>(cnt, dinv, N);
  const int NB = (N + 4095) / 4096;  // 25
  scan_p1<<<NB, 1024, 0, stream>>>(cnt, bsum, N);
  scan_p2<<<1, 1024, 0, stream>>>(bsum, NB);
  scan_p3<<<NB, 1024, 0, stream>>>(cnt, bsum, offs, curs, N);
  fill_csr<<<(E + 255) / 256, 256, 0, stream>>>(EI, curs, dinv, csr, E);

  const int pgrid = (N * OUT + 255) / 256;  // one wave per node
  // 10 propagation steps: 9 intermediate (bf16 out) + 1 final (fp32 out)
  prop_step<false><<<pgrid, 256, 0, stream>>>(H0b, hAb, nullptr, H0f, offs, csr, dinv, N);
  for (int i = 0; i < 4; ++i) {
    prop_step<false><<<pgrid, 256, 0, stream>>>(hAb, hBb, nullptr, H0f, offs, csr, dinv, N);
    prop_step<false><<<pgrid, 256, 0, stream>>>(hBb, hAb, nullptr, H0f, offs, csr, dinv, N);
  }
  prop_step<true><<<pgrid, 256, 0, stream>>>(hAb, nullptr, out, H0f, offs, csr, dinv, N);
}

// Round 10
// 1201.186 us; speedup vs baseline: 3.5361x; 1.0182x over previous
//
#include <hip/hip_runtime.h>
#include <hip/hip_bf16.h>
#include <hip/hip_fp16.h>

// APPNP: h = MLP(x); 10x { h = 0.9 * (D^-1/2 (A+I) D^-1/2) h + 0.1 * h0 }
// fp32 in/out; GEMMs run bf16 MFMA with inline fp32->bf16 conversion.
// R4: byte-diet (bf16 mirror of h, 4B/edge CSR).
// R5/R8 CSR builds REVERTED (global-atomic serialization / no XCD control).
// R7 (GEMM reg-prefetch) REVERTED. R9: global_load_lds. R10: gemm1 2-phase
//   double-buffer (out of top-5). R11 REVERTED. R12: multi-block scan.
// R13: h state bf16-only between prop steps (1223us best).
// R14: CSR build #4 — counting sort by dst>>9 with SCAN-DERIVED single-writer
//   positions (no global atomics anywhere in placement):
//   hist_a (LDS hist per 4096-edge block, digit-major mat) -> multi-block
//   scan of 200K mat -> scatter_a (LDS cursors; each (block,digit) range is
//   private+contiguous -> line-friendly stage writes) -> phase_b (block per
//   512-node bucket; LDS per-node cursors from offs; 65KB csr window is
//   single-writer L2-local -> full-line drains). Replaces fill_csr's 197MB
//   partial-line scatter (152us @ 1.4TB/s). stage aliases h1 (prep first).

typedef __bf16 bf16x8 __attribute__((ext_vector_type(8)));
typedef float f32x4 __attribute__((ext_vector_type(4)));

static constexpr int IN = 512, HID = 256, OUT = 64;
static constexpr int LDT = 40;   // LDS row stride (bf16 elems) for gemm2
static constexpr int CHB = 4096; // edges per counting-sort block
static constexpr int BSH = 9;    // nodes per bucket = 512; dst>>9 < 256

static __device__ __forceinline__ ushort f2bf(float f) {
  __hip_bfloat16 b = __float2bfloat16(f);
  return *reinterpret_cast<ushort*>(&b);
}
static __device__ __forceinline__ float bf2f(ushort u) {
  unsigned int x = ((unsigned int)u) << 16;
  return __uint_as_float(x);
}
// decode low-15-bit fp16 (sign=0) weight
static __device__ __forceinline__ float h15f(unsigned int u) {
  ushort hb = (ushort)(u & 0x7FFFu);
  __half h = *reinterpret_cast<__half*>(&hb);
  return __half2float(h);
}

static __device__ __forceinline__ void gload16(const void* g, void* l) {
  __builtin_amdgcn_global_load_lds(
      (const __attribute__((address_space(1))) void*)g,
      (__attribute__((address_space(3))) void*)l, 16, 0, 0);
}

// ---------------- transpose fp32 [K][C] -> bf16 [C][K] ----------------
__global__ void transpose_f32_bf16(const float* __restrict__ in, ushort* __restrict__ out,
                                   int K, int C) {
  int idx = blockIdx.x * 256 + threadIdx.x;
  if (idx < K * C) {
    int n = idx / K, k = idx % K;
    out[idx] = f2bf(in[k * C + n]);
  }
}

// ---------------- GEMM1: h1 = relu(X @ W1 + b1) ----------------
// X [M,512] fp32, W1T [256,512] bf16, h1 [M,256] bf16. Tile 128x128x32.
// global_load_lds into double-buffered LDS; A fp32 in LDS (cvt at frag read).
__global__ __launch_bounds__(256) void gemm1(const float* __restrict__ X,
                                             const ushort* __restrict__ W1T,
                                             const float* __restrict__ b1,
                                             ushort* __restrict__ h1, int M) {
  __shared__ __align__(16) float As[2][128 * 32];   // 2x16KB fp32, chunk-swizzled
  __shared__ __align__(16) ushort Bs[2][128 * 32];  // 2x8KB bf16, chunk-swizzled
  const int tid = threadIdx.x;
  const int m0 = blockIdx.y * 128;
  const int n0 = blockIdx.x * 128;
  const int lane = tid & 63, w = tid >> 6;
  const int wr = w >> 1, wc = w & 1;
  const int lm = lane & 15, lq = lane >> 4;
  const int wbase = w * 64;

  auto STAGE = [&](int k0, int buf) {
#pragma unroll
    for (int i = 0; i < 4; ++i) {
      int idx = i * 256 + tid;
      int row = idx >> 3, ch = idx & 7;
      int gm = m0 + row; gm = gm < M ? gm : M - 1;
      int sch = ch ^ (row & 7);
      gload16(&X[(size_t)gm * IN + k0 + sch * 4], &As[buf][(i * 256 + wbase) * 4]);
    }
#pragma unroll
    for (int i = 0; i < 2; ++i) {
      int idx = i * 256 + tid;
      int row = idx >> 2, ch = idx & 3;
      int sch = ch ^ ((row ^ (row >> 2)) & 3);
      gload16(&W1T[(size_t)(n0 + row) * IN + k0 + sch * 8], &Bs[buf][(i * 256 + wbase) * 8]);
    }
  };

  f32x4 acc[4][4] = {};

  STAGE(0, 0);
  __syncthreads();

  int cur = 0;
  for (int k0 = 0; k0 < IN; k0 += 32) {
    if (k0 + 32 < IN) STAGE(k0 + 32, cur ^ 1);

    bf16x8 af[4], bq[4];
#pragma unroll
    for (int mi = 0; mi < 4; ++mi) {
      int r = wr * 64 + mi * 16 + lm;
      int k7 = r & 7;
      float4 x0 = *reinterpret_cast<const float4*>(&As[cur][r * 32 + ((2 * lq) ^ k7) * 4]);
      float4 x1 = *reinterpret_cast<const float4*>(&As[cur][r * 32 + ((2 * lq + 1) ^ k7) * 4]);
      union { ushort u[8]; bf16x8 v; } cv;
      cv.u[0] = f2bf(x0.x); cv.u[1] = f2bf(x0.y); cv.u[2] = f2bf(x0.z); cv.u[3] = f2bf(x0.w);
      cv.u[4] = f2bf(x1.x); cv.u[5] = f2bf(x1.y); cv.u[6] = f2bf(x1.z); cv.u[7] = f2bf(x1.w);
      af[mi] = cv.v;
    }
#pragma unroll
    for (int ni = 0; ni < 4; ++ni) {
      int r = wc * 64 + ni * 16 + lm;
      int key = (r ^ (r >> 2)) & 3;
      bq[ni] = *reinterpret_cast<const bf16x8*>(&Bs[cur][r * 32 + (lq ^ key) * 8]);
    }
#pragma unroll
    for (int mi = 0; mi < 4; ++mi)
#pragma unroll
      for (int ni = 0; ni < 4; ++ni)
        acc[mi][ni] = __builtin_amdgcn_mfma_f32_16x16x32_bf16(af[mi], bq[ni], acc[mi][ni], 0, 0, 0);

    __syncthreads();
    cur ^= 1;
  }

#pragma unroll
  for (int ni = 0; ni < 4; ++ni) {
    int col = n0 + wc * 64 + ni * 16 + lm;
    float bias = b1[col];
#pragma unroll
    for (int mi = 0; mi < 4; ++mi) {
#pragma unroll
      for (int rg = 0; rg < 4; ++rg) {
        int row = m0 + wr * 64 + mi * 16 + lq * 4 + rg;
        if (row < M) {
          float v = acc[mi][ni][rg] + bias;
          v = v > 0.f ? v : 0.f;
          h1[(size_t)row * HID + col] = f2bf(v);
        }
      }
    }
  }
}

// ---------------- GEMM2: H0 = h1 @ W2 + b2, fp32 + bf16 mirror out ----------------
__global__ __launch_bounds__(256) void gemm2(const ushort* __restrict__ h1,
                                             const ushort* __restrict__ W2T,
                                             const float* __restrict__ b2,
                                             float* __restrict__ H0f,
                                             ushort* __restrict__ H0b, int M) {
  __shared__ __align__(16) ushort As[128 * LDT];
  __shared__ __align__(16) ushort Bs[64 * LDT];
  const int tid = threadIdx.x;
  const int m0 = blockIdx.x * 128;
  const int lane = tid & 63, w = tid >> 6;
  const int lm = lane & 15, lq = lane >> 4;
  const int c = tid & 3, r = tid >> 2;

  f32x4 acc[2][4] = {};

  for (int k0 = 0; k0 < HID; k0 += 32) {
#pragma unroll
    for (int rr = 0; rr < 2; ++rr) {
      int m = r + rr * 64;
      int gm = m0 + m; gm = gm < M ? gm : M - 1;
      *reinterpret_cast<int4*>(&As[m * LDT + c * 8]) =
          *reinterpret_cast<const int4*>(&h1[(size_t)gm * HID + k0 + c * 8]);
    }
    *reinterpret_cast<int4*>(&Bs[r * LDT + c * 8]) =
        *reinterpret_cast<const int4*>(&W2T[(size_t)r * HID + k0 + c * 8]);
    __syncthreads();
    bf16x8 af[2], bq[4];
#pragma unroll
    for (int mi = 0; mi < 2; ++mi)
      af[mi] = *reinterpret_cast<const bf16x8*>(&As[(w * 32 + mi * 16 + lm) * LDT + lq * 8]);
#pragma unroll
    for (int ni = 0; ni < 4; ++ni)
      bq[ni] = *reinterpret_cast<const bf16x8*>(&Bs[(ni * 16 + lm) * LDT + lq * 8]);
#pragma unroll
    for (int mi = 0; mi < 2; ++mi)
#pragma unroll
      for (int ni = 0; ni < 4; ++ni)
        acc[mi][ni] = __builtin_amdgcn_mfma_f32_16x16x32_bf16(af[mi], bq[ni], acc[mi][ni], 0, 0, 0);
    __syncthreads();
  }

#pragma unroll
  for (int ni = 0; ni < 4; ++ni) {
    int col = ni * 16 + lm;
    float bias = b2[col];
#pragma unroll
    for (int mi = 0; mi < 2; ++mi) {
#pragma unroll
      for (int rg = 0; rg < 4; ++rg) {
        int row = m0 + w * 32 + mi * 16 + lq * 4 + rg;
        if (row < M) {
          float v = acc[mi][ni][rg] + bias;
          H0f[(size_t)row * OUT + col] = v;
          H0b[(size_t)row * OUT + col] = f2bf(v);
        }
      }
    }
  }
}

// ---------------- degree / dinv / multi-block scan ----------------
__global__ void count_deg(const int* __restrict__ ei, int* __restrict__ cnt, int E) {
  int e = blockIdx.x * 256 + threadIdx.x;
  if (e < E) atomicAdd(&cnt[ei[E + e]], 1);
}

__global__ void calc_dinv(const int* __restrict__ cnt, float* __restrict__ dinv, int n) {
  int v = blockIdx.x * 256 + threadIdx.x;
  if (v < n) dinv[v] = rsqrtf((float)cnt[v] + 1.0f);  // +1: self-loop
}

// scan phase 1: per-block (4096-elem tile) totals
__global__ __launch_bounds__(1024) void scan_p1(const int* __restrict__ cnt,
                                                int* __restrict__ bsum, int n) {
  __shared__ int wsum[16];
  const int tid = threadIdx.x, lane = tid & 63, wid = tid >> 6;
  int i0 = blockIdx.x * 4096 + tid * 4;
  int s = 0;
#pragma unroll
  for (int j = 0; j < 4; ++j) s += (i0 + j < n) ? cnt[i0 + j] : 0;
#pragma unroll
  for (int d = 1; d < 64; d <<= 1) s += __shfl_xor(s, d, 64);
  if (lane == 0) wsum[wid] = s;
  __syncthreads();
  if (tid == 0) {
    int t = 0;
#pragma unroll
    for (int i = 0; i < 16; ++i) t += wsum[i];
    bsum[blockIdx.x] = t;
  }
}

// scan phase 2: single-block exclusive scan of bsum[nb] (nb <= 1024)
__global__ __launch_bounds__(1024) void scan_p2(int* __restrict__ bsum, int nb) {
  __shared__ int wsum[16];
  __shared__ int woff[16];
  const int tid = threadIdx.x, lane = tid & 63, wid = tid >> 6;
  int x = (tid < nb) ? bsum[tid] : 0;
  int val = x;
#pragma unroll
  for (int d = 1; d < 64; d <<= 1) {
    int t = __shfl_up(val, d, 64);
    if (lane >= d) val += t;
  }
  if (lane == 63) wsum[wid] = val;
  __syncthreads();
  if (wid == 0) {
    int s = (lane < 16) ? wsum[lane] : 0;
    int sv = s;
#pragma unroll
    for (int d = 1; d < 16; d <<= 1) {
      int t = __shfl_up(sv, d, 64);
      if (lane >= d) sv += t;
    }
    if (lane < 16) woff[lane] = sv - s;
  }
  __syncthreads();
  if (tid < nb) bsum[tid] = woff[wid] + (val - x);
}

// scan phase 3: per-block scan + block offset -> offs (exclusive); last writes offs[n]
__global__ __launch_bounds__(1024) void scan_p3(const int* __restrict__ cnt,
                                                const int* __restrict__ bsum,
                                                int* __restrict__ offs, int n) {
  __shared__ int wsum[16];
  __shared__ int woff[16];
  const int tid = threadIdx.x, lane = tid & 63, wid = tid >> 6;
  int i0 = blockIdx.x * 4096 + tid * 4;
  int x[4];
#pragma unroll
  for (int j = 0; j < 4; ++j) x[j] = (i0 + j < n) ? cnt[i0 + j] : 0;
  int tsum = x[0] + x[1] + x[2] + x[3];
  int val = tsum;
#pragma unroll
  for (int d = 1; d < 64; d <<= 1) {
    int t = __shfl_up(val, d, 64);
    if (lane >= d) val += t;
  }
  if (lane == 63) wsum[wid] = val;
  __syncthreads();
  if (wid == 0) {
    int s = (lane < 16) ? wsum[lane] : 0;
    int sv = s;
#pragma unroll
    for (int d = 1; d < 16; d <<= 1) {
      int t = __shfl_up(sv, d, 64);
      if (lane >= d) sv += t;
    }
    if (lane < 16) woff[lane] = sv - s;
  }
  __syncthreads();
  int excl = bsum[blockIdx.x] + woff[wid] + (val - tsum);
#pragma unroll
  for (int j = 0; j < 4; ++j) {
    if (i0 + j < n) offs[i0 + j] = excl;
    excl += x[j];
  }
  if (i0 < n && i0 + 4 >= n) offs[n] = excl;  // thread owning the last element
}

// ---------------- CSR build: counting sort by dst>>BSH ----------------
// hist: per-CHB-edge block LDS histogram over 256 buckets, digit-major out.
__global__ __launch_bounds__(256) void hist_a(const int* __restrict__ ei,
                                              int* __restrict__ mat, int E, int nblk) {
  __shared__ int h[256];
  h[threadIdx.x] = 0;
  __syncthreads();
  int e0 = blockIdx.x * CHB;
  int e1 = e0 + CHB; if (e1 > E) e1 = E;
  for (int e = e0 + threadIdx.x; e < e1; e += 256)
    atomicAdd(&h[ei[E + e] >> BSH], 1);
  __syncthreads();
  mat[threadIdx.x * nblk + blockIdx.x] = h[threadIdx.x];
}

// scatter: LDS cursors from scanned mat; each (block,digit) range is private
// and contiguous -> stage writes land in ~128B runs (line-friendly).
// record: x = (src<<15)|fp16bits(w) (w>0, sign bit free), y = dst.
__global__ __launch_bounds__(256) void scatter_a(const int* __restrict__ ei,
                                                 const int* __restrict__ mat,
                                                 const float* __restrict__ dinv,
                                                 uint2* __restrict__ stage,
                                                 int E, int nblk) {
  __shared__ int cur[256];
  cur[threadIdx.x] = mat[threadIdx.x * nblk + blockIdx.x];
  __syncthreads();
  int e0 = blockIdx.x * CHB;
  int e1 = e0 + CHB; if (e1 > E) e1 = E;
  for (int e = e0 + threadIdx.x; e < e1; e += 256) {
    int s = ei[e], d = ei[E + e];
    float w = dinv[s] * dinv[d];
    __half hw = __float2half(w);
    unsigned int hb = *reinterpret_cast<ushort*>(&hw);
    int p = atomicAdd(&cur[d >> BSH], 1);
    uint2 r;
    r.x = (((unsigned int)s) << 15) | hb;
    r.y = (unsigned int)d;
    stage[p] = r;
  }
}

// per-bucket scatter to final per-node csr slots. Block b owns nodes
// [b*512, b*512+512); its ~65KB csr window is single-writer and L2-local.
// stage segment == csr window indices (same counts, same ordering by bucket).
__global__ __launch_bounds__(256) void phase_b(const uint2* __restrict__ stage,
                                               const int* __restrict__ offs,
                                               unsigned int* __restrict__ csr, int n) {
  __shared__ int lcur[1 << BSH];
  const int n0 = blockIdx.x << BSH;
  int n1 = n0 + (1 << BSH); if (n1 > n) n1 = n;
  for (int t = threadIdx.x; t < (1 << BSH); t += 256) {
    int node = n0 + t;
    lcur[t] = (node < n) ? offs[node] : 0;
  }
  __syncthreads();
  const int e0 = offs[n0], e1 = offs[n1];
  for (int i = e0 + threadIdx.x; i < e1; i += 256) {
    uint2 r = stage[i];
    int p = atomicAdd(&lcur[r.y - (unsigned int)n0], 1);
    csr[p] = r.x;
  }
}

// ---------------- propagation: one wave per node, bf16 state only ----------------
// Lane l batch-fetches csr[base+l] (256B coalesced per 64 edges), shfl-broadcasts.
// 2 edges per load: lanes 0-31 read edge (j+2k) row as uint (features 2c,2c+1),
// lanes 32-63 read edge (j+2k+1). Even/odd-edge partial sums combined with
// shfl_xor(32). Self-loop read from the bf16 state; teleport h0 fp32.
// Intermediate: bf16 write only (half 1); FINAL: fp32 out write only (half 0).
template <bool FINAL>
__global__ __launch_bounds__(256) void prop_step(const ushort* __restrict__ hinb,
                                                 ushort* __restrict__ houtb,
                                                 float* __restrict__ out,
                                                 const float* __restrict__ h0,
                                                 const int* __restrict__ offs,
                                                 const unsigned int* __restrict__ csr,
                                                 const float* __restrict__ dinv, int n) {
  int gw = (blockIdx.x * 256 + threadIdx.x) >> 6;
  int lane = threadIdx.x & 63;
  if (gw >= n) return;
  const unsigned int* hin32 = (const unsigned int*)hinb;
  const int c = lane & 31;       // feature pair index (features 2c, 2c+1)
  const int half = lane >> 5;    // 0: even-slot edges, 1: odd-slot edges
  float alo[8], ahi[8];
#pragma unroll
  for (int k = 0; k < 8; ++k) { alo[k] = 0.f; ahi[k] = 0.f; }
  int e0 = offs[gw], e1 = offs[gw + 1];
  for (int base = e0; base < e1; base += 64) {
    int rem = e1 - base;
    // padded lanes: u=0 -> src=0, w=+0 (row 0 is valid; contribution is 0)
    unsigned int my = (lane < rem) ? csr[base + lane] : 0u;
    int cnt = rem < 64 ? rem : 64;
    int cnt32 = (cnt + 31) & ~31;
    for (int j = 0; j < cnt32; j += 32) {
      unsigned int u[16];
#pragma unroll
      for (int k = 0; k < 16; ++k)
        u[k] = (unsigned int)__shfl((int)my, j + 2 * k + half);
      unsigned int v[16];
#pragma unroll
      for (int k = 0; k < 16; ++k)
        v[k] = hin32[(size_t)(u[k] >> 15) * 32 + c];
#pragma unroll
      for (int k = 0; k < 16; ++k) {
        float w = h15f(u[k]);
        float f0 = __uint_as_float(v[k] << 16);
        float f1 = __uint_as_float(v[k] & 0xFFFF0000u);
        alo[k & 7] = fmaf(w, f0, alo[k & 7]);
        ahi[k & 7] = fmaf(w, f1, ahi[k & 7]);
      }
    }
  }
  float a0 = ((alo[0] + alo[1]) + (alo[2] + alo[3])) + ((alo[4] + alo[5]) + (alo[6] + alo[7]));
  float a1 = ((ahi[0] + ahi[1]) + (ahi[2] + ahi[3])) + ((ahi[4] + ahi[5]) + (ahi[6] + ahi[7]));
  // combine even/odd-edge halves (partner lane holds same features, other parity)
  a0 += __shfl_xor(a0, 32, 64);
  a1 += __shfl_xor(a1, 32, 64);
  float dv = dinv[gw];
  unsigned int sv = hin32[(size_t)gw * 32 + c];  // self row (bf16 state)
  float sx = __uint_as_float(sv << 16);
  float sy = __uint_as_float(sv & 0xFFFF0000u);
  float2 h0f = ((const float2*)h0)[(size_t)gw * 32 + c];
  float o0 = 0.9f * (a0 + dv * dv * sx) + 0.1f * h0f.x;
  float o1 = 0.9f * (a1 + dv * dv * sy) + 0.1f * h0f.y;
  if (FINAL) {
    if (half == 0) {
      float2 ov; ov.x = o0; ov.y = o1;
      ((float2*)out)[(size_t)gw * 32 + c] = ov;
    }
  } else {
    if (half == 1) {
      unsigned int pk = (unsigned int)f2bf(o0) | ((unsigned int)f2bf(o1) << 16);
      ((unsigned int*)houtb)[(size_t)gw * 32 + c] = pk;
    }
  }
}

extern "C" void kernel_launch(void* const* d_in, const int* in_sizes, int n_in,
                              void* d_out, int out_size, void* d_ws, size_t ws_size,
                              hipStream_t stream) {
  const float* X  = (const float*)d_in[0];  // [N,512] f32
  const int*   EI = (const int*)d_in[1];    // [2,E] int32
  const float* W1 = (const float*)d_in[2];  // [512,256] f32
  const float* b1 = (const float*)d_in[3];  // [256] f32
  const float* W2 = (const float*)d_in[4];  // [256,64] f32
  const float* b2 = (const float*)d_in[5];  // [64] f32
  float* out = (float*)d_out;               // [N,64] f32

  const int N = in_sizes[0] / IN;  // 100000
  const int E = in_sizes[1] / 2;   // 3200000

  char* ws = (char*)d_ws;
  size_t o = 0;
  auto alloc = [&](size_t b) {
    char* p = ws + o;
    o = (o + b + 255) & ~(size_t)255;
    return p;
  };
  float*  H0f  = (float*)alloc((size_t)N * OUT * 4);
  ushort* H0b  = (ushort*)alloc((size_t)N * OUT * 2);
  ushort* hAb  = (ushort*)alloc((size_t)N * OUT * 2);
  ushort* hBb  = (ushort*)alloc((size_t)N * OUT * 2);
  ushort* h1   = (ushort*)alloc((size_t)N * HID * 2);
  ushort* W1T  = (ushort*)alloc((size_t)IN * HID * 2);
  ushort* W2T  = (ushort*)alloc((size_t)HID * OUT * 2);
  int*    cnt  = (int*)alloc((size_t)N * 4);
  int*    offs = (int*)alloc((size_t)(N + 1) * 4);
  int*    bsum = (int*)alloc((size_t)1024 * 4);
  float*  dinv = (float*)alloc((size_t)N * 4);
  unsigned int* csr = (unsigned int*)alloc((size_t)E * 4);
  const int NBLK = (E + CHB - 1) / CHB;  // 782
  int*    mat  = (int*)alloc((size_t)256 * NBLK * 4);
  int*    msum = (int*)alloc((size_t)1024 * 4);
  // stage aliases h1 (E*8 = 25.6MB <= N*HID*2 = 51.2MB); consumed before gemm1.
  uint2*  stage = (uint2*)h1;
  (void)ws_size; (void)n_in; (void)out_size;

  transpose_f32_bf16<<<(IN * HID + 255) / 256, 256, 0, stream>>>(W1, W1T, IN, HID);
  transpose_f32_bf16<<<(HID * OUT + 255) / 256, 256, 0, stream>>>(W2, W2T, HID, OUT);

  // ---- graph prep (stage shares memory with h1 -> before gemm1) ----
  hipMemsetAsync(cnt, 0, (size_t)N * 4, stream);
  count_deg<<<(E + 255) / 256, 256, 0, stream>>>(EI, cnt, E);
  calc_dinv<<<(N + 255) / 256, 256, 0, stream>>>(cnt, dinv, N);
  const int NB = (N + 4095) / 4096;  // 25
  scan_p1<<<NB, 1024, 0, stream>>>(cnt, bsum, N);
  scan_p2<<<1, 1024, 0, stream>>>(bsum, NB);
  scan_p3<<<NB, 1024, 0, stream>>>(cnt, bsum, offs, N);

  const int MN = 256 * NBLK;           // 200192
  const int MB = (MN + 4095) / 4096;   // 49
  hist_a<<<NBLK, 256, 0, stream>>>(EI, mat, E, NBLK);
  scan_p1<<<MB, 1024, 0, stream>>>(mat, msum, MN);
  scan_p2<<<1, 1024, 0, stream>>>(msum, MB);
  scan_p3<<<MB, 1024, 0, stream>>>(mat, msum, mat, MN);  // in-place exclusive scan
  scatter_a<<<NBLK, 256, 0, stream>>>(EI, mat, dinv, stage, E, NBLK);
  const int NBKT = (N + (1 << BSH) - 1) >> BSH;  // 196
  phase_b<<<NBKT, 256, 0, stream>>>(stage, offs, csr, N);

  // ---- MLP ----
  gemm1<<<dim3(HID / 128, (N + 127) / 128), 256, 0, stream>>>(X, W1T, b1, h1, N);
  gemm2<<<(N + 127) / 128, 256, 0, stream>>>(h1, W2T, b2, H0f, H0b, N);

  const int pgrid = (N * OUT + 255) / 256;  // one wave per node
  // 10 propagation steps: 9 intermediate (bf16 out) + 1 final (fp32 out)
  prop_step<false><<<pgrid, 256, 0, stream>>>(H0b, hAb, nullptr, H0f, offs, csr, dinv, N);
  for (int i = 0; i < 4; ++i) {
    prop_step<false><<<pgrid, 256, 0, stream>>>(hAb, hBb, nullptr, H0f, offs, csr, dinv, N);
    prop_step<false><<<pgrid, 256, 0, stream>>>(hBb, hAb, nullptr, H0f, offs, csr, dinv, N);
  }
  prop_step<true><<<pgrid, 256, 0, stream>>>(hAb, nullptr, out, H0f, offs, csr, dinv, N);
}